// Round 10
// baseline (489.535 us; speedup 1.0000x reference)
//
#include <hip/hip_runtime.h>

// ---------------------------------------------------------------------------
// GCNPredictor: 3x (bf16 MFMA GEMM -> bf16 pull-gather+BNstats -> BN folded
// into next GEMM) + head.  N=50000, E=800000, D=H=128.
//
// Round-10: resubmission of round-9 (GPU acquisition timeout, kernel never
// ran). Gather unrolled 4-deep (latency-bound on L2-miss->L3 path); BN stats
// fused into gather (8-replica atomic sinks); BN finalize folded into
// consumer GEMM / head. k_bn_stats/k_bn_finalize removed.
//
// Workspace:
//   hw_b  [N*128] u16   GEMM output (message rows, bf16)
//   hbuf_b[N*128] u16   aggregation output (pre-BN, bf16)
//   dinv  [N] f32       rsqrt(weighted degree incl self-loop)
//   stats3[3][8*256]f32 per-layer 8-replica col sum/sumsq
//   cnt/ptr/bsum/rank   CSC build (int)
//   emeta [E] int2      CSC: (src row, coef bits)
// ---------------------------------------------------------------------------

typedef unsigned short u16;
typedef unsigned int u32;
typedef unsigned long long u64;
typedef short bf16x8 __attribute__((ext_vector_type(8)));
typedef float f32x4 __attribute__((ext_vector_type(4)));

__device__ inline float bf2f(u16 u) { return __uint_as_float(((u32)u) << 16); }
__device__ inline u16 f2bf(float f) {          // RTNE, finite inputs
  u32 u = __float_as_uint(f);
  return (u16)((u + 0x7FFFu + ((u >> 16) & 1u)) >> 16);
}

// ---------------- CSC build ------------------------------------------------
__global__ __launch_bounds__(256) void k_zero_cnt(int* cnt, int n) {
  int i = blockIdx.x * 256 + threadIdx.x;
  if (i < n) cnt[i] = 0;
}

__global__ __launch_bounds__(256) void k_count_rank(const int* __restrict__ col,
                                                    int* __restrict__ cnt,
                                                    int* __restrict__ rank, int e) {
  int i = blockIdx.x * 256 + threadIdx.x;
  if (i < e) rank[i] = atomicAdd(&cnt[col[i]], 1);
}

__global__ __launch_bounds__(256) void k_scan1(const int* __restrict__ cnt,
                                               int* __restrict__ ptr,
                                               int* __restrict__ bsum, int n) {
  __shared__ int sh[256];
  int t = threadIdx.x;
  int i = blockIdx.x * 256 + t;
  int v = (i < n) ? cnt[i] : 0;
  sh[t] = v;
  __syncthreads();
  for (int d = 1; d < 256; d <<= 1) {
    int u = (t >= d) ? sh[t - d] : 0;
    __syncthreads();
    sh[t] += u;
    __syncthreads();
  }
  if (i < n) ptr[i] = sh[t] - v;
  if (t == 255) bsum[blockIdx.x] = sh[255];
}

__global__ __launch_bounds__(256) void k_scan2(int* __restrict__ bsum, int nb) {
  __shared__ int sh[256];
  int t = threadIdx.x;
  int v = (t < nb) ? bsum[t] : 0;
  sh[t] = v;
  __syncthreads();
  for (int d = 1; d < 256; d <<= 1) {
    int u = (t >= d) ? sh[t - d] : 0;
    __syncthreads();
    sh[t] += u;
    __syncthreads();
  }
  if (t < nb) bsum[t] = sh[t] - v;
}

__global__ __launch_bounds__(256) void k_scan3(int* __restrict__ ptr,
                                               const int* __restrict__ bsum,
                                               int n, int e) {
  int i = blockIdx.x * 256 + threadIdx.x;
  if (i < n) ptr[i] += bsum[blockIdx.x];
  if (i == 0) ptr[n] = e;
}

__global__ __launch_bounds__(256) void k_fill(const int* __restrict__ row,
                                              const int* __restrict__ col,
                                              const float* __restrict__ w,
                                              const int* __restrict__ ptr,
                                              const int* __restrict__ rank,
                                              int2* __restrict__ emeta, int e) {
  int i = blockIdx.x * 256 + threadIdx.x;
  if (i < e) {
    int pos = ptr[col[i]] + rank[i];
    emeta[pos] = make_int2(row[i], __float_as_int(w[i]));
  }
}

__global__ __launch_bounds__(256) void k_deg_dinv(const int* __restrict__ ptr,
                                                  const int2* __restrict__ emeta,
                                                  float* __restrict__ dinv, int n) {
  int i = blockIdx.x * 256 + threadIdx.x;
  if (i >= n) return;
  int j = ptr[i], end = ptr[i + 1];
  float d = 1.0f;
  for (; j < end; ++j) d += __int_as_float(emeta[j].y);
  dinv[i] = rsqrtf(d);
}

__global__ __launch_bounds__(256) void k_coef(const int* __restrict__ ptr,
                                              int2* __restrict__ emeta,
                                              const float* __restrict__ dinv, int n) {
  int i = blockIdx.x * 256 + threadIdx.x;
  if (i >= n) return;
  float dc = dinv[i];
  int j = ptr[i], end = ptr[i + 1];
  for (; j < end; ++j) {
    int2 m = emeta[j];
    emeta[j] = make_int2(m.x, __float_as_int(dinv[m.x] * __int_as_float(m.y) * dc));
  }
}

// ---------------- bf16 MFMA GEMM -------------------------------------------
// C[n x 128](bf16) = act(A)[n x 128] * W[128 x 128].
// act: if Sprev != null, BN affine of prev layer computed from 8-replica
// stats (A=g*istd, B=be-mu*A) into LDS, then relu(v*A+B) during staging.
// Block 0 zeroes THIS layer's stats buffer Szero (consumed by k_gather next).
// Tile 128x128, 4 waves. LDS cells: 8B (4 bf16 along k), cell (r,k4) at
// [r*32 + (k4 ^ (r&15))] -> conflict-free b64 fragment reads. A- and B-
// fragments use the identical (lane,elem)->k rule (k-permutation invariant).
// C/D: col=lane&15, row=(lane>>4)*4+reg (m89-verified).
__global__ __launch_bounds__(256) void k_gemm(const void* __restrict__ Ain,
                                              int a_is_f32,
                                              const float* __restrict__ W,
                                              u16* __restrict__ C,
                                              const float* __restrict__ Sprev,
                                              const float* __restrict__ g,
                                              const float* __restrict__ be,
                                              float* __restrict__ Szero,
                                              int n) {
  __shared__ u64 As64[128 * 32];   // 32 KB
  __shared__ u64 Ws64[128 * 32];   // 32 KB
  __shared__ float absh[256];      // folded BN affine A,B
  int t = threadIdx.x;
  if (blockIdx.x == 0) {           // zero this layer's stats sinks
#pragma unroll
    for (int i = 0; i < 8; ++i) Szero[t + 256 * i] = 0.f;
  }
  if (Sprev) {
    if (t < 128) {
      float s = 0.f, ss = 0.f;
#pragma unroll
      for (int r2 = 0; r2 < 8; ++r2) {
        s += Sprev[r2 * 256 + t];
        ss += Sprev[r2 * 256 + 128 + t];
      }
      float inv_n = 1.0f / (float)n;
      float mu = s * inv_n;
      float var = ss * inv_n - mu * mu;
      float istd = rsqrtf(var + 1e-5f);
      float A = g[t] * istd;
      absh[t] = A;
      absh[128 + t] = fmaf(-mu, A, be[t]);
    }
    __syncthreads();
  }

  int row0 = blockIdx.x * 128;
  int nr = min(128, n - row0);

  if (a_is_f32) {                  // layer 0: fp32 input, no affine
    const float4* src = (const float4*)((const float*)Ain + (size_t)row0 * 128);
#pragma unroll
    for (int i = 0; i < 16; ++i) {
      int idx = t + 256 * i;       // float4 id within tile
      int r = idx >> 5;
      int j4 = idx & 31;           // cell k4 = j4
      float4 v = (r < nr) ? src[idx] : make_float4(0.f, 0.f, 0.f, 0.f);
      u64 cell = (u64)f2bf(v.x) | ((u64)f2bf(v.y) << 16) |
                 ((u64)f2bf(v.z) << 32) | ((u64)f2bf(v.w) << 48);
      As64[r * 32 + (j4 ^ (r & 15))] = cell;
    }
  } else {                         // bf16 input (+ optional affine+relu)
    const u16* A = (const u16*)Ain;
#pragma unroll
    for (int i = 0; i < 8; ++i) {
      int idx = t + 256 * i;       // 16B chunk id
      int r = idx >> 4;
      int c8 = idx & 15;           // 8-bf16 chunk
      u64 lo = 0, hi = 0;
      if (r < nr) {
        const u64* srcq = (const u64*)(A + ((size_t)(row0 + r)) * 128 + c8 * 8);
        lo = srcq[0]; hi = srcq[1];
        if (Sprev) {
          u64 nl = 0, nh = 0;
#pragma unroll
          for (int j = 0; j < 4; ++j) {
            int c = c8 * 8 + j;
            float f = fmaxf(fmaf(bf2f((u16)(lo >> (16 * j))), absh[c], absh[128 + c]), 0.f);
            nl |= ((u64)f2bf(f)) << (16 * j);
            int c2 = c + 4;
            float f2 = fmaxf(fmaf(bf2f((u16)(hi >> (16 * j))), absh[c2], absh[128 + c2]), 0.f);
            nh |= ((u64)f2bf(f2)) << (16 * j);
          }
          lo = nl; hi = nh;
        }
      }
      As64[r * 32 + ((c8 * 2) ^ (r & 15))] = lo;
      As64[r * 32 + ((c8 * 2 + 1) ^ (r & 15))] = hi;
    }
  }
  {  // stage W transposed: cell (col, k4) = W[k4*4 .. +3][col]
    int col = t & 127;
    int khalf = t >> 7;
#pragma unroll
    for (int kk = 0; kk < 16; ++kk) {
      int k4 = khalf * 16 + kk;
      int k = k4 * 4;
      u64 cell = (u64)f2bf(W[(size_t)(k + 0) * 128 + col]) |
                 ((u64)f2bf(W[(size_t)(k + 1) * 128 + col]) << 16) |
                 ((u64)f2bf(W[(size_t)(k + 2) * 128 + col]) << 32) |
                 ((u64)f2bf(W[(size_t)(k + 3) * 128 + col]) << 48);
      Ws64[col * 32 + (k4 ^ (col & 15))] = cell;
    }
  }
  __syncthreads();

  int w = t >> 6, l = t & 63;
  int lr = l & 15, kg = l >> 4;
  int rA0 = w * 32 + lr, rA1 = rA0 + 16;   // rA&15 == lr
  f32x4 acc[2][8];
#pragma unroll
  for (int m = 0; m < 2; ++m)
#pragma unroll
    for (int nf = 0; nf < 8; ++nf) acc[m][nf] = (f32x4){0.f, 0.f, 0.f, 0.f};

  union Frag { u64 q[2]; bf16x8 v; };
#pragma unroll
  for (int ks = 0; ks < 4; ++ks) {
    int kb = ks * 8 + kg;
    Frag a0, a1;
    a0.q[0] = As64[rA0 * 32 + (kb ^ lr)];
    a0.q[1] = As64[rA0 * 32 + ((kb + 4) ^ lr)];
    a1.q[0] = As64[rA1 * 32 + (kb ^ lr)];
    a1.q[1] = As64[rA1 * 32 + ((kb + 4) ^ lr)];
#pragma unroll
    for (int nf = 0; nf < 8; ++nf) {
      Frag b;
      b.q[0] = Ws64[(nf * 16 + lr) * 32 + (kb ^ lr)];
      b.q[1] = Ws64[(nf * 16 + lr) * 32 + ((kb + 4) ^ lr)];
      acc[0][nf] = __builtin_amdgcn_mfma_f32_16x16x32_bf16(a0.v, b.v, acc[0][nf], 0, 0, 0);
      acc[1][nf] = __builtin_amdgcn_mfma_f32_16x16x32_bf16(a1.v, b.v, acc[1][nf], 0, 0, 0);
    }
  }
#pragma unroll
  for (int m = 0; m < 2; ++m)
#pragma unroll
    for (int nf = 0; nf < 8; ++nf)
#pragma unroll
      for (int j = 0; j < 4; ++j) {
        int gr = row0 + w * 32 + m * 16 + kg * 4 + j;
        if (gr < n) C[(size_t)gr * 128 + nf * 16 + lr] = f2bf(acc[m][nf][j]);
      }
}

// ---------------- bf16 pull-gather + fused BN stats ------------------------
// One wave per node; lane owns 2 columns. 4-edge unrolled (4 row loads in
// flight). Wave's stats contribution = (ax, ay, ax^2, ay^2); block-reduced
// in LDS, atomically added to replica (blockIdx&7) of this layer's stats.
__global__ __launch_bounds__(256) void k_gather(const u16* __restrict__ hw,
                                                const int* __restrict__ ptr,
                                                const int2* __restrict__ emeta,
                                                const float* __restrict__ dinv,
                                                u16* __restrict__ out,
                                                float* __restrict__ stats, int n) {
  int node = blockIdx.x * 4 + (threadIdx.x >> 6);
  int lane = threadIdx.x & 63;
  float ax = 0.f, ay = 0.f;
  if (node < n) {
    float di = dinv[node];
    u32 su = ((const u32*)(hw + (size_t)node * 128))[lane];
    ax = bf2f((u16)su) * di * di;
    ay = bf2f((u16)(su >> 16)) * di * di;
    int j = ptr[node], end = ptr[node + 1];
    for (; j + 3 < end; j += 4) {
      int2 m0 = emeta[j], m1 = emeta[j + 1], m2 = emeta[j + 2], m3 = emeta[j + 3];
      float c0 = __int_as_float(m0.y), c1 = __int_as_float(m1.y);
      float c2 = __int_as_float(m2.y), c3 = __int_as_float(m3.y);
      u32 v0 = ((const u32*)(hw + (size_t)m0.x * 128))[lane];
      u32 v1 = ((const u32*)(hw + (size_t)m1.x * 128))[lane];
      u32 v2 = ((const u32*)(hw + (size_t)m2.x * 128))[lane];
      u32 v3 = ((const u32*)(hw + (size_t)m3.x * 128))[lane];
      ax = fmaf(bf2f((u16)v0), c0, ax); ay = fmaf(bf2f((u16)(v0 >> 16)), c0, ay);
      ax = fmaf(bf2f((u16)v1), c1, ax); ay = fmaf(bf2f((u16)(v1 >> 16)), c1, ay);
      ax = fmaf(bf2f((u16)v2), c2, ax); ay = fmaf(bf2f((u16)(v2 >> 16)), c2, ay);
      ax = fmaf(bf2f((u16)v3), c3, ax); ay = fmaf(bf2f((u16)(v3 >> 16)), c3, ay);
    }
    for (; j < end; ++j) {
      int2 m0 = emeta[j];
      float c0 = __int_as_float(m0.y);
      u32 v0 = ((const u32*)(hw + (size_t)m0.x * 128))[lane];
      ax = fmaf(bf2f((u16)v0), c0, ax); ay = fmaf(bf2f((u16)(v0 >> 16)), c0, ay);
    }
    u32 o = (u32)f2bf(ax) | ((u32)f2bf(ay) << 16);
    ((u32*)(out + (size_t)node * 128))[lane] = o;
  }
  __shared__ float4 red[256];
  red[threadIdx.x] = make_float4(ax, ay, ax * ax, ay * ay);
  __syncthreads();
  if (threadIdx.x < 64) {
    int t = threadIdx.x;
    float4 a = red[t], b = red[t + 64], c = red[t + 128], d = red[t + 192];
    float* S = stats + (blockIdx.x & 7) * 256;
    unsafeAtomicAdd(&S[2 * t],           a.x + b.x + c.x + d.x);
    unsafeAtomicAdd(&S[2 * t + 1],       a.y + b.y + c.y + d.y);
    unsafeAtomicAdd(&S[128 + 2 * t],     a.z + b.z + c.z + d.z);
    unsafeAtomicAdd(&S[128 + 2 * t + 1], a.w + b.w + c.w + d.w);
  }
}

// ---------------- head -----------------------------------------------------
// BN3 affine from 8-replica stats, rows 0,1 -> relu -> Wh+bh -> relu -> dots.
__global__ __launch_bounds__(256) void k_head(const u16* __restrict__ h,
                                              const float* __restrict__ S,
                                              const float* __restrict__ g,
                                              const float* __restrict__ be,
                                              const float* __restrict__ Wh,
                                              const float* __restrict__ bh,
                                              const float* __restrict__ Wa,
                                              const float* __restrict__ ba,
                                              const float* __restrict__ Wz,
                                              const float* __restrict__ bz,
                                              float* __restrict__ out, int n) {
  __shared__ float habs[256];
  __shared__ float hrow[256];
  __shared__ float red[256];
  int t = threadIdx.x;
  if (t < 128) {
    float s = 0.f, ss = 0.f;
#pragma unroll
    for (int r2 = 0; r2 < 8; ++r2) {
      s += S[r2 * 256 + t];
      ss += S[r2 * 256 + 128 + t];
    }
    float inv_n = 1.0f / (float)n;
    float mu = s * inv_n;
    float var = ss * inv_n - mu * mu;
    float istd = rsqrtf(var + 1e-5f);
    float A = g[t] * istd;
    habs[t] = A;
    habs[128 + t] = fmaf(-mu, A, be[t]);
  }
  __syncthreads();
  {
    int c = t & 127;
    hrow[t] = fmaxf(fmaf(bf2f(h[t]), habs[c], habs[128 + c]), 0.f);
  }
  __syncthreads();
  int j = t & 127, r = t >> 7;
  float acc = bh[j];
  for (int k = 0; k < 128; ++k)
    acc = fmaf(hrow[r * 128 + k], Wh[k * 128 + j], acc);
  float hv = fmaxf(acc, 0.f);
  float wv = (r == 0) ? Wa[j] : Wz[j];
  red[t] = hv * wv;
  __syncthreads();
  for (int s = 64; s >= 1; s >>= 1) {
    if (j < s) red[t] += red[t + s];
    __syncthreads();
  }
  if (t == 0) out[0] = red[0] + ba[0];
  if (t == 128) out[1] = red[128] + bz[0];
}

extern "C" void kernel_launch(void* const* d_in, const int* in_sizes, int n_in,
                              void* d_out, int out_size, void* d_ws, size_t ws_size,
                              hipStream_t stream) {
  const float* x  = (const float*)d_in[0];
  const int*   ei = (const int*)d_in[1];
  const float* ew = (const float*)d_in[2];
  const float* W[3]  = {(const float*)d_in[3], (const float*)d_in[5], (const float*)d_in[7]};
  // b1/b2/b3 cancel inside BatchNorm -> skipped.
  const float* g[3]  = {(const float*)d_in[9],  (const float*)d_in[11], (const float*)d_in[13]};
  const float* be[3] = {(const float*)d_in[10], (const float*)d_in[12], (const float*)d_in[14]};
  const float* Wh = (const float*)d_in[15];
  const float* bh = (const float*)d_in[16];
  const float* Wa = (const float*)d_in[17];
  const float* ba = (const float*)d_in[18];
  const float* Wz = (const float*)d_in[19];
  const float* bz = (const float*)d_in[20];

  const int n = in_sizes[0] / 128;
  const int e = in_sizes[1] / 2;
  const int* row = ei;
  const int* col = ei + e;

  u16*   hw_b   = (u16*)d_ws;
  u16*   hbuf_b = hw_b + (size_t)n * 128;
  float* dinv   = (float*)(hbuf_b + (size_t)n * 128);
  float* stats3 = dinv + n;               // 3 * 8 * 256
  int*   cnt    = (int*)(stats3 + 3 * 2048);
  int*   ptr    = cnt + n;
  int*   bsum   = ptr + n + 1;            // 256
  int*   rank   = bsum + 256;             // E
  uintptr_t pm  = ((uintptr_t)(rank + e) + 15) & ~(uintptr_t)15;
  int2*  emeta  = (int2*)pm;              // E

  const int nb_n = (n + 255) / 256;
  const int nb_e = (e + 255) / 256;

  k_zero_cnt<<<nb_n, 256, 0, stream>>>(cnt, n);
  k_count_rank<<<nb_e, 256, 0, stream>>>(col, cnt, rank, e);
  k_scan1<<<nb_n, 256, 0, stream>>>(cnt, ptr, bsum, n);
  k_scan2<<<1, 256, 0, stream>>>(bsum, nb_n);
  k_scan3<<<nb_n, 256, 0, stream>>>(ptr, bsum, n, e);
  k_fill<<<nb_e, 256, 0, stream>>>(row, col, ew, ptr, rank, emeta, e);
  k_deg_dinv<<<nb_n, 256, 0, stream>>>(ptr, emeta, dinv, n);
  k_coef<<<nb_n, 256, 0, stream>>>(ptr, emeta, dinv, n);

  for (int l = 0; l < 3; ++l) {
    const void* hin = (l == 0) ? (const void*)x : (const void*)hbuf_b;
    const float* Sprev = (l == 0) ? nullptr : (stats3 + (l - 1) * 2048);
    const float* gp = (l == 0) ? nullptr : g[l - 1];
    const float* bp = (l == 0) ? nullptr : be[l - 1];
    k_gemm<<<(n + 127) / 128, 256, 0, stream>>>(hin, (l == 0) ? 1 : 0, W[l],
                                                hw_b, Sprev, gp, bp,
                                                stats3 + l * 2048, n);
    k_gather<<<(n + 3) / 4, 256, 0, stream>>>(hw_b, ptr, emeta, dinv, hbuf_b,
                                              stats3 + l * 2048, n);
  }
  k_head<<<1, 256, 0, stream>>>(hbuf_b, stats3 + 2 * 2048, g[2], be[2],
                                Wh, bh, Wa, ba, Wz, bz, (float*)d_out, n);
}

// Round 11
// 377.314 us; speedup vs baseline: 1.2974x; 1.2974x over previous
//
#include <hip/hip_runtime.h>

// ---------------------------------------------------------------------------
// GCNPredictor: 3x (bf16 MFMA GEMM -> bf16 pull-gather+BNstats -> BN folded
// into next GEMM) + head.  N=50000, E=800000, D=H=128.
//
// Round-11: fix round-10's atomic storm (3.2M fabric atomics onto 8KB ->
// +35us/gather, +25MB writes). Gather blocks now cover 16 nodes (register-
// accumulated stats, one flush per block) -> 800K atomics over 64 replicas
// (49 blocks/replica). Tiny k_bn_finalize reduces replicas -> affine ab.
//
// Workspace:
//   hw_b  [N*128] u16     GEMM output (message rows, bf16)
//   hbuf_b[N*128] u16     aggregation output (pre-BN, bf16)
//   dinv  [N] f32         rsqrt(weighted degree incl self-loop)
//   stats3[3][64*256] f32 per-layer 64-replica col sum/sumsq
//   ab    [3*256] f32     per-layer folded BN affine A,B
//   cnt/ptr/bsum/rank     CSC build (int)
//   emeta [E] int2        CSC: (src row, coef bits)
// ---------------------------------------------------------------------------

typedef unsigned short u16;
typedef unsigned int u32;
typedef unsigned long long u64;
typedef short bf16x8 __attribute__((ext_vector_type(8)));
typedef float f32x4 __attribute__((ext_vector_type(4)));

#define NREP 64   // stats replicas per layer

__device__ inline float bf2f(u16 u) { return __uint_as_float(((u32)u) << 16); }
__device__ inline u16 f2bf(float f) {          // RTNE, finite inputs
  u32 u = __float_as_uint(f);
  return (u16)((u + 0x7FFFu + ((u >> 16) & 1u)) >> 16);
}

// ---------------- CSC build ------------------------------------------------
__global__ __launch_bounds__(256) void k_zero_cnt(int* cnt, int n) {
  int i = blockIdx.x * 256 + threadIdx.x;
  if (i < n) cnt[i] = 0;
}

__global__ __launch_bounds__(256) void k_count_rank(const int* __restrict__ col,
                                                    int* __restrict__ cnt,
                                                    int* __restrict__ rank, int e) {
  int i = blockIdx.x * 256 + threadIdx.x;
  if (i < e) rank[i] = atomicAdd(&cnt[col[i]], 1);
}

__global__ __launch_bounds__(256) void k_scan1(const int* __restrict__ cnt,
                                               int* __restrict__ ptr,
                                               int* __restrict__ bsum, int n) {
  __shared__ int sh[256];
  int t = threadIdx.x;
  int i = blockIdx.x * 256 + t;
  int v = (i < n) ? cnt[i] : 0;
  sh[t] = v;
  __syncthreads();
  for (int d = 1; d < 256; d <<= 1) {
    int u = (t >= d) ? sh[t - d] : 0;
    __syncthreads();
    sh[t] += u;
    __syncthreads();
  }
  if (i < n) ptr[i] = sh[t] - v;
  if (t == 255) bsum[blockIdx.x] = sh[255];
}

__global__ __launch_bounds__(256) void k_scan2(int* __restrict__ bsum, int nb) {
  __shared__ int sh[256];
  int t = threadIdx.x;
  int v = (t < nb) ? bsum[t] : 0;
  sh[t] = v;
  __syncthreads();
  for (int d = 1; d < 256; d <<= 1) {
    int u = (t >= d) ? sh[t - d] : 0;
    __syncthreads();
    sh[t] += u;
    __syncthreads();
  }
  if (t < nb) bsum[t] = sh[t] - v;
}

__global__ __launch_bounds__(256) void k_scan3(int* __restrict__ ptr,
                                               const int* __restrict__ bsum,
                                               int n, int e) {
  int i = blockIdx.x * 256 + threadIdx.x;
  if (i < n) ptr[i] += bsum[blockIdx.x];
  if (i == 0) ptr[n] = e;
}

__global__ __launch_bounds__(256) void k_fill(const int* __restrict__ row,
                                              const int* __restrict__ col,
                                              const float* __restrict__ w,
                                              const int* __restrict__ ptr,
                                              const int* __restrict__ rank,
                                              int2* __restrict__ emeta, int e) {
  int i = blockIdx.x * 256 + threadIdx.x;
  if (i < e) {
    int pos = ptr[col[i]] + rank[i];
    emeta[pos] = make_int2(row[i], __float_as_int(w[i]));
  }
}

__global__ __launch_bounds__(256) void k_deg_dinv(const int* __restrict__ ptr,
                                                  const int2* __restrict__ emeta,
                                                  float* __restrict__ dinv, int n) {
  int i = blockIdx.x * 256 + threadIdx.x;
  if (i >= n) return;
  int j = ptr[i], end = ptr[i + 1];
  float d = 1.0f;
  for (; j < end; ++j) d += __int_as_float(emeta[j].y);
  dinv[i] = rsqrtf(d);
}

__global__ __launch_bounds__(256) void k_coef(const int* __restrict__ ptr,
                                              int2* __restrict__ emeta,
                                              const float* __restrict__ dinv, int n) {
  int i = blockIdx.x * 256 + threadIdx.x;
  if (i >= n) return;
  float dc = dinv[i];
  int j = ptr[i], end = ptr[i + 1];
  for (; j < end; ++j) {
    int2 m = emeta[j];
    emeta[j] = make_int2(m.x, __float_as_int(dinv[m.x] * __int_as_float(m.y) * dc));
  }
}

// ---------------- bf16 MFMA GEMM -------------------------------------------
// C[n x 128](bf16) = act(A)[n x 128] * W[128 x 128].
// act = relu(v*A+B) with (A,B)=ab (prev layer's folded BN affine), or
// identity for layer 0. Blocks 0..15 zero this layer's 64-replica stats.
// Tile 128x128, 4 waves. LDS cells: 8B (4 bf16 along k), cell (r,k4) at
// [r*32 + (k4 ^ (r&15))] -> conflict-free b64 fragment reads. A- and B-
// fragments use the identical (lane,elem)->k rule (k-permutation invariant).
// C/D: col=lane&15, row=(lane>>4)*4+reg (m89-verified).
__global__ __launch_bounds__(256) void k_gemm(const void* __restrict__ Ain,
                                              int a_is_f32,
                                              const float* __restrict__ W,
                                              u16* __restrict__ C,
                                              const float* __restrict__ ab,
                                              float* __restrict__ Szero,
                                              int n) {
  __shared__ u64 As64[128 * 32];   // 32 KB
  __shared__ u64 Ws64[128 * 32];   // 32 KB
  __shared__ float absh[256];      // folded BN affine A,B
  int t = threadIdx.x;
  if (blockIdx.x < 16) {           // zero this layer's 64-replica stats
#pragma unroll
    for (int i = 0; i < 4; ++i)
      Szero[blockIdx.x * 1024 + t + 256 * i] = 0.f;
  }
  if (ab) {
    if (t < 128) {
      absh[t] = ab[t];
      absh[128 + t] = ab[128 + t];
    }
    __syncthreads();
  }

  int row0 = blockIdx.x * 128;
  int nr = min(128, n - row0);

  if (a_is_f32) {                  // layer 0: fp32 input, no affine
    const float4* src = (const float4*)((const float*)Ain + (size_t)row0 * 128);
#pragma unroll
    for (int i = 0; i < 16; ++i) {
      int idx = t + 256 * i;       // float4 id within tile
      int r = idx >> 5;
      int j4 = idx & 31;           // cell k4 = j4
      float4 v = (r < nr) ? src[idx] : make_float4(0.f, 0.f, 0.f, 0.f);
      u64 cell = (u64)f2bf(v.x) | ((u64)f2bf(v.y) << 16) |
                 ((u64)f2bf(v.z) << 32) | ((u64)f2bf(v.w) << 48);
      As64[r * 32 + (j4 ^ (r & 15))] = cell;
    }
  } else {                         // bf16 input (+ optional affine+relu)
    const u16* A = (const u16*)Ain;
#pragma unroll
    for (int i = 0; i < 8; ++i) {
      int idx = t + 256 * i;       // 16B chunk id
      int r = idx >> 4;
      int c8 = idx & 15;           // 8-bf16 chunk
      u64 lo = 0, hi = 0;
      if (r < nr) {
        const u64* srcq = (const u64*)(A + ((size_t)(row0 + r)) * 128 + c8 * 8);
        lo = srcq[0]; hi = srcq[1];
        if (ab) {
          u64 nl = 0, nh = 0;
#pragma unroll
          for (int j = 0; j < 4; ++j) {
            int c = c8 * 8 + j;
            float f = fmaxf(fmaf(bf2f((u16)(lo >> (16 * j))), absh[c], absh[128 + c]), 0.f);
            nl |= ((u64)f2bf(f)) << (16 * j);
            int c2 = c + 4;
            float f2 = fmaxf(fmaf(bf2f((u16)(hi >> (16 * j))), absh[c2], absh[128 + c2]), 0.f);
            nh |= ((u64)f2bf(f2)) << (16 * j);
          }
          lo = nl; hi = nh;
        }
      }
      As64[r * 32 + ((c8 * 2) ^ (r & 15))] = lo;
      As64[r * 32 + ((c8 * 2 + 1) ^ (r & 15))] = hi;
    }
  }
  {  // stage W transposed: cell (col, k4) = W[k4*4 .. +3][col]
    int col = t & 127;
    int khalf = t >> 7;
#pragma unroll
    for (int kk = 0; kk < 16; ++kk) {
      int k4 = khalf * 16 + kk;
      int k = k4 * 4;
      u64 cell = (u64)f2bf(W[(size_t)(k + 0) * 128 + col]) |
                 ((u64)f2bf(W[(size_t)(k + 1) * 128 + col]) << 16) |
                 ((u64)f2bf(W[(size_t)(k + 2) * 128 + col]) << 32) |
                 ((u64)f2bf(W[(size_t)(k + 3) * 128 + col]) << 48);
      Ws64[col * 32 + (k4 ^ (col & 15))] = cell;
    }
  }
  __syncthreads();

  int w = t >> 6, l = t & 63;
  int lr = l & 15, kg = l >> 4;
  int rA0 = w * 32 + lr, rA1 = rA0 + 16;   // rA&15 == lr
  f32x4 acc[2][8];
#pragma unroll
  for (int m = 0; m < 2; ++m)
#pragma unroll
    for (int nf = 0; nf < 8; ++nf) acc[m][nf] = (f32x4){0.f, 0.f, 0.f, 0.f};

  union Frag { u64 q[2]; bf16x8 v; };
#pragma unroll
  for (int ks = 0; ks < 4; ++ks) {
    int kb = ks * 8 + kg;
    Frag a0, a1;
    a0.q[0] = As64[rA0 * 32 + (kb ^ lr)];
    a0.q[1] = As64[rA0 * 32 + ((kb + 4) ^ lr)];
    a1.q[0] = As64[rA1 * 32 + (kb ^ lr)];
    a1.q[1] = As64[rA1 * 32 + ((kb + 4) ^ lr)];
#pragma unroll
    for (int nf = 0; nf < 8; ++nf) {
      Frag b;
      b.q[0] = Ws64[(nf * 16 + lr) * 32 + (kb ^ lr)];
      b.q[1] = Ws64[(nf * 16 + lr) * 32 + ((kb + 4) ^ lr)];
      acc[0][nf] = __builtin_amdgcn_mfma_f32_16x16x32_bf16(a0.v, b.v, acc[0][nf], 0, 0, 0);
      acc[1][nf] = __builtin_amdgcn_mfma_f32_16x16x32_bf16(a1.v, b.v, acc[1][nf], 0, 0, 0);
    }
  }
#pragma unroll
  for (int m = 0; m < 2; ++m)
#pragma unroll
    for (int nf = 0; nf < 8; ++nf)
#pragma unroll
      for (int j = 0; j < 4; ++j) {
        int gr = row0 + w * 32 + m * 16 + kg * 4 + j;
        if (gr < n) C[(size_t)gr * 128 + nf * 16 + lr] = f2bf(acc[m][nf][j]);
      }
}

// ---------------- bf16 pull-gather + fused BN stats ------------------------
// Block covers 16 nodes (4 iterations x 4 waves); per-thread stats accumulate
// in registers across iterations; ONE LDS reduce + 256 atomics per block into
// replica (blockIdx & 63). 4-edge unrolled row loads (4 in flight).
__global__ __launch_bounds__(256) void k_gather(const u16* __restrict__ hw,
                                                const int* __restrict__ ptr,
                                                const int2* __restrict__ emeta,
                                                const float* __restrict__ dinv,
                                                u16* __restrict__ out,
                                                float* __restrict__ stats, int n) {
  int w = threadIdx.x >> 6;
  int lane = threadIdx.x & 63;
  float sx = 0.f, sy = 0.f, sxx = 0.f, syy = 0.f;
#pragma unroll
  for (int it = 0; it < 4; ++it) {
    int node = blockIdx.x * 16 + it * 4 + w;
    if (node < n) {
      float di = dinv[node];
      u32 su = ((const u32*)(hw + (size_t)node * 128))[lane];
      float ax = bf2f((u16)su) * di * di;
      float ay = bf2f((u16)(su >> 16)) * di * di;
      int j = ptr[node], end = ptr[node + 1];
      for (; j + 3 < end; j += 4) {
        int2 m0 = emeta[j], m1 = emeta[j + 1], m2 = emeta[j + 2], m3 = emeta[j + 3];
        float c0 = __int_as_float(m0.y), c1 = __int_as_float(m1.y);
        float c2 = __int_as_float(m2.y), c3 = __int_as_float(m3.y);
        u32 v0 = ((const u32*)(hw + (size_t)m0.x * 128))[lane];
        u32 v1 = ((const u32*)(hw + (size_t)m1.x * 128))[lane];
        u32 v2 = ((const u32*)(hw + (size_t)m2.x * 128))[lane];
        u32 v3 = ((const u32*)(hw + (size_t)m3.x * 128))[lane];
        ax = fmaf(bf2f((u16)v0), c0, ax); ay = fmaf(bf2f((u16)(v0 >> 16)), c0, ay);
        ax = fmaf(bf2f((u16)v1), c1, ax); ay = fmaf(bf2f((u16)(v1 >> 16)), c1, ay);
        ax = fmaf(bf2f((u16)v2), c2, ax); ay = fmaf(bf2f((u16)(v2 >> 16)), c2, ay);
        ax = fmaf(bf2f((u16)v3), c3, ax); ay = fmaf(bf2f((u16)(v3 >> 16)), c3, ay);
      }
      for (; j < end; ++j) {
        int2 m0 = emeta[j];
        float c0 = __int_as_float(m0.y);
        u32 v0 = ((const u32*)(hw + (size_t)m0.x * 128))[lane];
        ax = fmaf(bf2f((u16)v0), c0, ax); ay = fmaf(bf2f((u16)(v0 >> 16)), c0, ay);
      }
      u32 o = (u32)f2bf(ax) | ((u32)f2bf(ay) << 16);
      ((u32*)(out + (size_t)node * 128))[lane] = o;
      sx += ax; sy += ay;
      sxx = fmaf(ax, ax, sxx); syy = fmaf(ay, ay, syy);
    }
  }
  __shared__ float4 red[256];
  red[threadIdx.x] = make_float4(sx, sy, sxx, syy);
  __syncthreads();
  if (threadIdx.x < 64) {
    int t = threadIdx.x;
    float4 a = red[t], b = red[t + 64], c = red[t + 128], d = red[t + 192];
    float* S = stats + (blockIdx.x & (NREP - 1)) * 256;
    unsafeAtomicAdd(&S[2 * t],           a.x + b.x + c.x + d.x);
    unsafeAtomicAdd(&S[2 * t + 1],       a.y + b.y + c.y + d.y);
    unsafeAtomicAdd(&S[128 + 2 * t],     a.z + b.z + c.z + d.z);
    unsafeAtomicAdd(&S[128 + 2 * t + 1], a.w + b.w + c.w + d.w);
  }
}

// ---------------- BN finalize: reduce replicas -> folded affine ------------
__global__ __launch_bounds__(128) void k_bn_finalize(const float* __restrict__ S,
                                                     const float* __restrict__ g,
                                                     const float* __restrict__ be,
                                                     float* __restrict__ ab, int n) {
  int c = threadIdx.x;
  float s = 0.f, ss = 0.f;
#pragma unroll 8
  for (int r = 0; r < NREP; ++r) {
    s += S[r * 256 + c];
    ss += S[r * 256 + 128 + c];
  }
  float inv_n = 1.0f / (float)n;
  float mu = s * inv_n;
  float var = ss * inv_n - mu * mu;
  float istd = rsqrtf(var + 1e-5f);
  float A = g[c] * istd;
  ab[c] = A;
  ab[128 + c] = fmaf(-mu, A, be[c]);
}

// ---------------- head -----------------------------------------------------
// rows 0,1: BN3 affine (ab) + relu -> Wh+bh -> relu -> dots with Wa/Wz.
__global__ __launch_bounds__(256) void k_head(const u16* __restrict__ h,
                                              const float* __restrict__ ab,
                                              const float* __restrict__ Wh,
                                              const float* __restrict__ bh,
                                              const float* __restrict__ Wa,
                                              const float* __restrict__ ba,
                                              const float* __restrict__ Wz,
                                              const float* __restrict__ bz,
                                              float* __restrict__ out) {
  __shared__ float hrow[256];
  __shared__ float red[256];
  int t = threadIdx.x;
  {
    int c = t & 127;
    hrow[t] = fmaxf(fmaf(bf2f(h[t]), ab[c], ab[128 + c]), 0.f);
  }
  __syncthreads();
  int j = t & 127, r = t >> 7;
  float acc = bh[j];
  for (int k = 0; k < 128; ++k)
    acc = fmaf(hrow[r * 128 + k], Wh[k * 128 + j], acc);
  float hv = fmaxf(acc, 0.f);
  float wv = (r == 0) ? Wa[j] : Wz[j];
  red[t] = hv * wv;
  __syncthreads();
  for (int s = 64; s >= 1; s >>= 1) {
    if (j < s) red[t] += red[t + s];
    __syncthreads();
  }
  if (t == 0) out[0] = red[0] + ba[0];
  if (t == 128) out[1] = red[128] + bz[0];
}

extern "C" void kernel_launch(void* const* d_in, const int* in_sizes, int n_in,
                              void* d_out, int out_size, void* d_ws, size_t ws_size,
                              hipStream_t stream) {
  const float* x  = (const float*)d_in[0];
  const int*   ei = (const int*)d_in[1];
  const float* ew = (const float*)d_in[2];
  const float* W[3]  = {(const float*)d_in[3], (const float*)d_in[5], (const float*)d_in[7]};
  // b1/b2/b3 cancel inside BatchNorm -> skipped.
  const float* g[3]  = {(const float*)d_in[9],  (const float*)d_in[11], (const float*)d_in[13]};
  const float* be[3] = {(const float*)d_in[10], (const float*)d_in[12], (const float*)d_in[14]};
  const float* Wh = (const float*)d_in[15];
  const float* bh = (const float*)d_in[16];
  const float* Wa = (const float*)d_in[17];
  const float* ba = (const float*)d_in[18];
  const float* Wz = (const float*)d_in[19];
  const float* bz = (const float*)d_in[20];

  const int n = in_sizes[0] / 128;
  const int e = in_sizes[1] / 2;
  const int* row = ei;
  const int* col = ei + e;

  u16*   hw_b   = (u16*)d_ws;
  u16*   hbuf_b = hw_b + (size_t)n * 128;
  float* dinv   = (float*)(hbuf_b + (size_t)n * 128);
  float* stats3 = dinv + n;               // 3 * NREP * 256
  float* ab     = stats3 + 3 * NREP * 256;  // 3 * 256
  int*   cnt    = (int*)(ab + 3 * 256);
  int*   ptr    = cnt + n;
  int*   bsum   = ptr + n + 1;            // 256
  int*   rank   = bsum + 256;             // E
  uintptr_t pm  = ((uintptr_t)(rank + e) + 15) & ~(uintptr_t)15;
  int2*  emeta  = (int2*)pm;              // E

  const int nb_n = (n + 255) / 256;
  const int nb_e = (e + 255) / 256;

  k_zero_cnt<<<nb_n, 256, 0, stream>>>(cnt, n);
  k_count_rank<<<nb_e, 256, 0, stream>>>(col, cnt, rank, e);
  k_scan1<<<nb_n, 256, 0, stream>>>(cnt, ptr, bsum, n);
  k_scan2<<<1, 256, 0, stream>>>(bsum, nb_n);
  k_scan3<<<nb_n, 256, 0, stream>>>(ptr, bsum, n, e);
  k_fill<<<nb_e, 256, 0, stream>>>(row, col, ew, ptr, rank, emeta, e);
  k_deg_dinv<<<nb_n, 256, 0, stream>>>(ptr, emeta, dinv, n);
  k_coef<<<nb_n, 256, 0, stream>>>(ptr, emeta, dinv, n);

  for (int l = 0; l < 3; ++l) {
    const void* hin = (l == 0) ? (const void*)x : (const void*)hbuf_b;
    const float* abp = (l == 0) ? nullptr : (ab + (l - 1) * 256);
    k_gemm<<<(n + 127) / 128, 256, 0, stream>>>(hin, (l == 0) ? 1 : 0, W[l],
                                                hw_b, abp,
                                                stats3 + l * NREP * 256, n);
    k_gather<<<(n + 15) / 16, 256, 0, stream>>>(hw_b, ptr, emeta, dinv, hbuf_b,
                                                stats3 + l * NREP * 256, n);
    k_bn_finalize<<<1, 128, 0, stream>>>(stats3 + l * NREP * 256, g[l], be[l],
                                         ab + l * 256, n);
  }
  k_head<<<1, 256, 0, stream>>>(hbuf_b, ab + 2 * 256, Wh, bh, Wa, ba, Wz, bz,
                                (float*)d_out);
}